// Round 4
// baseline (63.892 us; speedup 1.0000x reference)
//
#include <hip/hip_runtime.h>

#define B_ 8
#define S_ 4096
#define D_ 1024
#define N_ 128
#define K_ 8
#define NEG_INF_ (-1e9f)

// ---------------- Kernel 0: zero-fill out_masked (pure streaming stores) -----
__global__ void zero_fill_kernel(float4* __restrict__ p, int n4) {
    int i = blockIdx.x * blockDim.x + threadIdx.x;
    const int stride = gridDim.x * blockDim.x;
    const float4 z = make_float4(0.f, 0.f, 0.f, 0.f);
    for (; i < n4; i += stride) p[i] = z;
}

// ---------------- Kernel 1: per-token dot with cls_w (balanced GEMV) ----------
__global__ void tok_dot_kernel(const float* __restrict__ h,
                               const float* __restrict__ cls_w,
                               float* __restrict__ tok_dot) {   // [B*S]
    const int lane = threadIdx.x & 63;
    const int gw = (blockIdx.x << 2) + (threadIdx.x >> 6);  // global wave id, 0..8191
    const int dofs = lane * 4;

    const float4 w0 = *reinterpret_cast<const float4*>(cls_w + 0 * 256 + dofs);
    const float4 w1 = *reinterpret_cast<const float4*>(cls_w + 1 * 256 + dofs);
    const float4 w2 = *reinterpret_cast<const float4*>(cls_w + 2 * 256 + dofs);
    const float4 w3 = *reinterpret_cast<const float4*>(cls_w + 3 * 256 + dofs);

    for (int token = gw; token < B_ * S_; token += 8192) {
        const float* p = h + (size_t)token * D_;
        const float4 v0 = *reinterpret_cast<const float4*>(p + 0 * 256 + dofs);
        const float4 v1 = *reinterpret_cast<const float4*>(p + 1 * 256 + dofs);
        const float4 v2 = *reinterpret_cast<const float4*>(p + 2 * 256 + dofs);
        const float4 v3 = *reinterpret_cast<const float4*>(p + 3 * 256 + dofs);
        float acc = v0.x * w0.x + v0.y * w0.y + v0.z * w0.z + v0.w * w0.w
                  + v1.x * w1.x + v1.y * w1.y + v1.z * w1.z + v1.w * w1.w
                  + v2.x * w2.x + v2.y * w2.y + v2.z * w2.z + v2.w * w2.w
                  + v3.x * w3.x + v3.y * w3.y + v3.z * w3.z + v3.w * w3.w;
        for (int off = 32; off > 0; off >>= 1) acc += __shfl_down(acc, off, 64);
        if (lane == 0) tok_dot[token] = acc;
    }
}

// ---------------- Kernel 2: segment-sum + greedy selection + mask + ranges ---
// One block per batch. Produces selected, logits, out_mask (gather via LDS),
// and the K picked sentences' token ranges for the sparse copy.
__global__ void select_kernel(const float* __restrict__ tok_dot,  // [B,S]
                              const int* __restrict__ ind,        // [B,S]
                              const float* __restrict__ cls_b,    // [1]
                              float* __restrict__ out_selected,   // [B,N]
                              float* __restrict__ out_logits,     // [K,B,N]
                              float* __restrict__ out_mask,       // [B,S]
                              int* __restrict__ ranges) {         // [B,K,2]
    const int b = blockIdx.x;
    const int tid = threadIdx.x;  // 256 threads

    __shared__ float td[S_];
    __shared__ int   si[S_];
    __shared__ float red_val[N_];
    __shared__ int   red_idx[N_];
    __shared__ float s_dotcur, s_lencur;
    __shared__ int   s_picks[K_];
    __shared__ int   seg0[N_], seg1[N_];
    __shared__ float sel_sh[N_];

    for (int s = tid; s < S_; s += 256) {
        td[s] = tok_dot[b * S_ + s];
        si[s] = ind[b * S_ + s];
    }
    if (tid == 0) { s_dotcur = 0.f; s_lencur = 0.f; }
    __syncthreads();

    float dseg = 0.f, len = 1.f, smask = 0.f, sel = 0.f;
    if (tid < N_) {
        const int n = tid;
        int lo = 0, hi = S_;
        while (lo < hi) { int mid = (lo + hi) >> 1; if (si[mid] < n) lo = mid + 1; else hi = mid; }
        const int s0 = lo;
        lo = s0; hi = S_;
        while (lo < hi) { int mid = (lo + hi) >> 1; if (si[mid] < n + 1) lo = mid + 1; else hi = mid; }
        const int s1 = lo;
        seg0[tid] = s0; seg1[tid] = s1;
        float acc = 0.f;
        for (int s = s0; s < s1; ++s) acc += td[s];
        dseg  = acc;
        len   = fmaxf((float)(s1 - s0), 1.0f);
        smask = (s1 > s0) ? 1.f : 0.f;
    }
    const float bias = cls_b[0];
    __syncthreads();

    for (int k = 0; k < K_; ++k) {
        if (tid < N_) {
            float logit = (s_dotcur + dseg) / (s_lencur + len) + bias;
            logit = (smask > 0.f) ? logit : NEG_INF_;
            out_logits[(size_t)k * (B_ * N_) + b * N_ + tid] = logit;
            red_val[tid] = logit;
            red_idx[tid] = tid;
        }
        __syncthreads();
        for (int off = 64; off > 0; off >>= 1) {
            if (tid < off) {
                float v2 = red_val[tid + off]; int i2 = red_idx[tid + off];
                if (v2 > red_val[tid] || (v2 == red_val[tid] && i2 < red_idx[tid])) {
                    red_val[tid] = v2; red_idx[tid] = i2;
                }
            }
            __syncthreads();
        }
        const int pick = red_idx[0];
        if (tid == pick) {
            smask = 0.f; sel = 1.f;
            s_dotcur += dseg;
            s_lencur += len;
            s_picks[k] = pick;
        }
        __syncthreads();
    }

    if (tid < N_) {
        sel_sh[tid] = sel;
        out_selected[b * N_ + tid] = sel;
    }
    __syncthreads();
    if (tid < K_) {
        const int p = s_picks[tid];
        ranges[(b * K_ + tid) * 2]     = seg0[p];
        ranges[(b * K_ + tid) * 2 + 1] = seg1[p];
    }
    for (int s = tid; s < S_; s += 256) {
        out_mask[b * S_ + s] = sel_sh[si[s]];
    }
}

// ---------------- Kernel 3: sparse copy of selected tokens -------------------
// Grid-strides over only the selected tokens (~K per batch * avg 32 tokens).
// h is L3-resident after tok_dot, so reads are cheap. m == 1 for selected.
__global__ void sparse_copy_kernel(const float* __restrict__ h,
                                   const int* __restrict__ ranges,   // [B,K,2]
                                   float* __restrict__ out_masked) { // [B,S,D]
    // redundant, wave-uniform prefix computation (128 ints, L2-hot)
    int bpref[B_ + 1];
    bpref[0] = 0;
    #pragma unroll
    for (int b = 0; b < B_; ++b) {
        int c = 0;
        #pragma unroll
        for (int k = 0; k < K_; ++k)
            c += ranges[(b * K_ + k) * 2 + 1] - ranges[(b * K_ + k) * 2];
        bpref[b + 1] = bpref[b] + c;
    }
    const int total = bpref[B_];
    const int tid = threadIdx.x;

    for (int w = blockIdx.x; w < total; w += gridDim.x) {
        int b = 0;
        while (w >= bpref[b + 1]) ++b;
        int off = w - bpref[b];
        int s = 0;
        #pragma unroll
        for (int k = 0; k < K_; ++k) {
            const int s0 = ranges[(b * K_ + k) * 2];
            const int s1 = ranges[(b * K_ + k) * 2 + 1];
            const int l = s1 - s0;
            if (off < l) { s = s0 + off; off = 0x7fffffff; }  // found
            else if (off != 0x7fffffff) off -= l;
        }
        const size_t base = ((size_t)b * S_ + s) * D_ + tid * 4;
        *reinterpret_cast<float4*>(out_masked + base) =
            *reinterpret_cast<const float4*>(h + base);
    }
}

extern "C" void kernel_launch(void* const* d_in, const int* in_sizes, int n_in,
                              void* d_out, int out_size, void* d_ws, size_t ws_size,
                              hipStream_t stream) {
    const float* h     = (const float*)d_in[0];
    const int*   ind   = (const int*)d_in[1];
    const float* cls_w = (const float*)d_in[2];
    const float* cls_b = (const float*)d_in[3];

    float* out = (float*)d_out;
    float* out_selected = out;                         // [B,N]    1024
    float* out_logits   = out + 1024;                  // [K,B,N]  8192
    float* out_mask     = out + 1024 + 8192;           // [B,S]    32768
    float* out_masked   = out + 1024 + 8192 + 32768;   // [B,S,D]

    char* ws = (char*)d_ws;
    float* tok_dot = (float*)ws;                              // B*S floats = 128 KB
    int*   ranges  = (int*)(ws + (size_t)B_ * S_ * 4);        // B*K*2 ints

    const int n4 = B_ * S_ * D_ / 4;   // float4 count of out_masked
    zero_fill_kernel<<<dim3(2048), dim3(256), 0, stream>>>(
        reinterpret_cast<float4*>(out_masked), n4);
    tok_dot_kernel<<<dim3(2048), dim3(256), 0, stream>>>(h, cls_w, tok_dot);
    select_kernel<<<dim3(B_), dim3(256), 0, stream>>>(tok_dot, ind, cls_b,
                                                      out_selected, out_logits,
                                                      out_mask, ranges);
    sparse_copy_kernel<<<dim3(2048), dim3(256), 0, stream>>>(h, ranges, out_masked);
}

// Round 5
// 63.781 us; speedup vs baseline: 1.0017x; 1.0017x over previous
//
#include <hip/hip_runtime.h>

#define B_ 8
#define S_ 4096
#define D_ 1024
#define N_ 128
#define K_ 8
#define NEG_INF_ (-1e9f)

// ------- Kernel 1: fused per-token dot + zero-fill of out_masked -------------
// One wave per token per iteration. Lane reads 4 float4s of h (the whole
// token, coalesced), accumulates the dot with cls_w, AND writes zeros to the
// same-shaped out_masked locations. Read and write streams co-issue, so the
// memory system runs bidirectionally like a D2D copy (~6.3 TB/s aggregate)
// instead of two serialized unidirectional kernels.
__global__ void dot_zero_kernel(const float* __restrict__ h,
                                const float* __restrict__ cls_w,
                                float* __restrict__ tok_dot,      // [B*S]
                                float* __restrict__ out_masked) { // [B,S,D]
    const int lane = threadIdx.x & 63;
    const int gw = (blockIdx.x << 2) + (threadIdx.x >> 6);  // global wave id, 0..8191
    const int dofs = lane * 4;

    const float4 w0 = *reinterpret_cast<const float4*>(cls_w + 0 * 256 + dofs);
    const float4 w1 = *reinterpret_cast<const float4*>(cls_w + 1 * 256 + dofs);
    const float4 w2 = *reinterpret_cast<const float4*>(cls_w + 2 * 256 + dofs);
    const float4 w3 = *reinterpret_cast<const float4*>(cls_w + 3 * 256 + dofs);
    const float4 z = make_float4(0.f, 0.f, 0.f, 0.f);

    for (int token = gw; token < B_ * S_; token += 8192) {
        const float* p = h + (size_t)token * D_;
        float* q = out_masked + (size_t)token * D_;
        const float4 v0 = *reinterpret_cast<const float4*>(p + 0 * 256 + dofs);
        const float4 v1 = *reinterpret_cast<const float4*>(p + 1 * 256 + dofs);
        const float4 v2 = *reinterpret_cast<const float4*>(p + 2 * 256 + dofs);
        const float4 v3 = *reinterpret_cast<const float4*>(p + 3 * 256 + dofs);
        *reinterpret_cast<float4*>(q + 0 * 256 + dofs) = z;
        *reinterpret_cast<float4*>(q + 1 * 256 + dofs) = z;
        *reinterpret_cast<float4*>(q + 2 * 256 + dofs) = z;
        *reinterpret_cast<float4*>(q + 3 * 256 + dofs) = z;
        float acc = v0.x * w0.x + v0.y * w0.y + v0.z * w0.z + v0.w * w0.w
                  + v1.x * w1.x + v1.y * w1.y + v1.z * w1.z + v1.w * w1.w
                  + v2.x * w2.x + v2.y * w2.y + v2.z * w2.z + v2.w * w2.w
                  + v3.x * w3.x + v3.y * w3.y + v3.z * w3.z + v3.w * w3.w;
        for (int off = 32; off > 0; off >>= 1) acc += __shfl_down(acc, off, 64);
        if (lane == 0) tok_dot[token] = acc;
    }
}

// ---------------- Kernel 2: segment-sum + greedy selection + mask + ranges ---
// One block per batch. Produces selected, logits, out_mask (gather via LDS),
// and the K picked sentences' token ranges for the sparse copy.
__global__ void select_kernel(const float* __restrict__ tok_dot,  // [B,S]
                              const int* __restrict__ ind,        // [B,S]
                              const float* __restrict__ cls_b,    // [1]
                              float* __restrict__ out_selected,   // [B,N]
                              float* __restrict__ out_logits,     // [K,B,N]
                              float* __restrict__ out_mask,       // [B,S]
                              int* __restrict__ ranges) {         // [B,K,2]
    const int b = blockIdx.x;
    const int tid = threadIdx.x;  // 256 threads

    __shared__ float td[S_];
    __shared__ int   si[S_];
    __shared__ float red_val[N_];
    __shared__ int   red_idx[N_];
    __shared__ float s_dotcur, s_lencur;
    __shared__ int   s_picks[K_];
    __shared__ int   seg0[N_], seg1[N_];
    __shared__ float sel_sh[N_];

    for (int s = tid; s < S_; s += 256) {
        td[s] = tok_dot[b * S_ + s];
        si[s] = ind[b * S_ + s];
    }
    if (tid == 0) { s_dotcur = 0.f; s_lencur = 0.f; }
    __syncthreads();

    float dseg = 0.f, len = 1.f, smask = 0.f, sel = 0.f;
    if (tid < N_) {
        const int n = tid;
        int lo = 0, hi = S_;
        while (lo < hi) { int mid = (lo + hi) >> 1; if (si[mid] < n) lo = mid + 1; else hi = mid; }
        const int s0 = lo;
        lo = s0; hi = S_;
        while (lo < hi) { int mid = (lo + hi) >> 1; if (si[mid] < n + 1) lo = mid + 1; else hi = mid; }
        const int s1 = lo;
        seg0[tid] = s0; seg1[tid] = s1;
        float acc = 0.f;
        for (int s = s0; s < s1; ++s) acc += td[s];
        dseg  = acc;
        len   = fmaxf((float)(s1 - s0), 1.0f);
        smask = (s1 > s0) ? 1.f : 0.f;
    }
    const float bias = cls_b[0];
    __syncthreads();

    for (int k = 0; k < K_; ++k) {
        if (tid < N_) {
            float logit = (s_dotcur + dseg) / (s_lencur + len) + bias;
            logit = (smask > 0.f) ? logit : NEG_INF_;
            out_logits[(size_t)k * (B_ * N_) + b * N_ + tid] = logit;
            red_val[tid] = logit;
            red_idx[tid] = tid;
        }
        __syncthreads();
        for (int off = 64; off > 0; off >>= 1) {
            if (tid < off) {
                float v2 = red_val[tid + off]; int i2 = red_idx[tid + off];
                if (v2 > red_val[tid] || (v2 == red_val[tid] && i2 < red_idx[tid])) {
                    red_val[tid] = v2; red_idx[tid] = i2;
                }
            }
            __syncthreads();
        }
        const int pick = red_idx[0];
        if (tid == pick) {
            smask = 0.f; sel = 1.f;
            s_dotcur += dseg;
            s_lencur += len;
            s_picks[k] = pick;
        }
        __syncthreads();
    }

    if (tid < N_) {
        sel_sh[tid] = sel;
        out_selected[b * N_ + tid] = sel;
    }
    __syncthreads();
    if (tid < K_) {
        const int p = s_picks[tid];
        ranges[(b * K_ + tid) * 2]     = seg0[p];
        ranges[(b * K_ + tid) * 2 + 1] = seg1[p];
    }
    for (int s = tid; s < S_; s += 256) {
        out_mask[b * S_ + s] = sel_sh[si[s]];
    }
}

// ---------------- Kernel 3: sparse copy of selected tokens -------------------
// Grid-strides over only the selected tokens (~K per batch * avg 32 tokens).
// h is L3-resident after dot_zero, so reads are cheap.
__global__ void sparse_copy_kernel(const float* __restrict__ h,
                                   const int* __restrict__ ranges,   // [B,K,2]
                                   float* __restrict__ out_masked) { // [B,S,D]
    int bpref[B_ + 1];
    bpref[0] = 0;
    #pragma unroll
    for (int b = 0; b < B_; ++b) {
        int c = 0;
        #pragma unroll
        for (int k = 0; k < K_; ++k)
            c += ranges[(b * K_ + k) * 2 + 1] - ranges[(b * K_ + k) * 2];
        bpref[b + 1] = bpref[b] + c;
    }
    const int total = bpref[B_];
    const int tid = threadIdx.x;

    for (int w = blockIdx.x; w < total; w += gridDim.x) {
        int b = 0;
        while (w >= bpref[b + 1]) ++b;
        int off = w - bpref[b];
        int s = 0;
        #pragma unroll
        for (int k = 0; k < K_; ++k) {
            const int s0 = ranges[(b * K_ + k) * 2];
            const int s1 = ranges[(b * K_ + k) * 2 + 1];
            const int l = s1 - s0;
            if (off < l) { s = s0 + off; off = 0x7fffffff; }  // found
            else if (off != 0x7fffffff) off -= l;
        }
        const size_t base = ((size_t)b * S_ + s) * D_ + tid * 4;
        *reinterpret_cast<float4*>(out_masked + base) =
            *reinterpret_cast<const float4*>(h + base);
    }
}

extern "C" void kernel_launch(void* const* d_in, const int* in_sizes, int n_in,
                              void* d_out, int out_size, void* d_ws, size_t ws_size,
                              hipStream_t stream) {
    const float* h     = (const float*)d_in[0];
    const int*   ind   = (const int*)d_in[1];
    const float* cls_w = (const float*)d_in[2];
    const float* cls_b = (const float*)d_in[3];

    float* out = (float*)d_out;
    float* out_selected = out;                         // [B,N]    1024
    float* out_logits   = out + 1024;                  // [K,B,N]  8192
    float* out_mask     = out + 1024 + 8192;           // [B,S]    32768
    float* out_masked   = out + 1024 + 8192 + 32768;   // [B,S,D]

    char* ws = (char*)d_ws;
    float* tok_dot = (float*)ws;                              // B*S floats = 128 KB
    int*   ranges  = (int*)(ws + (size_t)B_ * S_ * 4);        // B*K*2 ints

    dot_zero_kernel<<<dim3(2048), dim3(256), 0, stream>>>(h, cls_w, tok_dot, out_masked);
    select_kernel<<<dim3(B_), dim3(256), 0, stream>>>(tok_dot, ind, cls_b,
                                                      out_selected, out_logits,
                                                      out_mask, ranges);
    sparse_copy_kernel<<<dim3(2048), dim3(256), 0, stream>>>(h, ranges, out_masked);
}

// Round 6
// 56.677 us; speedup vs baseline: 1.1273x; 1.1254x over previous
//
#include <hip/hip_runtime.h>

#define B_ 8
#define S_ 4096
#define D_ 1024
#define N_ 128
#define K_ 8
#define NEG_INF_ (-1e9f)

// ---------------- Kernel 1: per-token dot with cls_w (pure-read phase) -------
// One wave per token-pair iteration: 2-token unroll keeps 8 float4 loads in
// flight before the (latency-bound) shuffle reduce chains. 8192 waves, each
// handles tokens {gw, gw+8192} then {gw+16384, gw+24576}.
__global__ void tok_dot_kernel(const float* __restrict__ h,
                               const float* __restrict__ cls_w,
                               float* __restrict__ tok_dot) {   // [B*S]
    const int lane = threadIdx.x & 63;
    const int gw = (blockIdx.x << 2) + (threadIdx.x >> 6);  // 0..8191
    const int dofs = lane * 4;

    const float4 w0 = *reinterpret_cast<const float4*>(cls_w + 0 * 256 + dofs);
    const float4 w1 = *reinterpret_cast<const float4*>(cls_w + 1 * 256 + dofs);
    const float4 w2 = *reinterpret_cast<const float4*>(cls_w + 2 * 256 + dofs);
    const float4 w3 = *reinterpret_cast<const float4*>(cls_w + 3 * 256 + dofs);

    #pragma unroll
    for (int t = 0; t < 2; ++t) {
        const int tokA = gw + t * 16384;
        const int tokB = tokA + 8192;
        const float* pA = h + (size_t)tokA * D_;
        const float* pB = h + (size_t)tokB * D_;
        const float4 a0 = *reinterpret_cast<const float4*>(pA + 0 * 256 + dofs);
        const float4 a1 = *reinterpret_cast<const float4*>(pA + 1 * 256 + dofs);
        const float4 a2 = *reinterpret_cast<const float4*>(pA + 2 * 256 + dofs);
        const float4 a3 = *reinterpret_cast<const float4*>(pA + 3 * 256 + dofs);
        const float4 b0 = *reinterpret_cast<const float4*>(pB + 0 * 256 + dofs);
        const float4 b1 = *reinterpret_cast<const float4*>(pB + 1 * 256 + dofs);
        const float4 b2 = *reinterpret_cast<const float4*>(pB + 2 * 256 + dofs);
        const float4 b3 = *reinterpret_cast<const float4*>(pB + 3 * 256 + dofs);
        float accA = a0.x * w0.x + a0.y * w0.y + a0.z * w0.z + a0.w * w0.w
                   + a1.x * w1.x + a1.y * w1.y + a1.z * w1.z + a1.w * w1.w
                   + a2.x * w2.x + a2.y * w2.y + a2.z * w2.z + a2.w * w2.w
                   + a3.x * w3.x + a3.y * w3.y + a3.z * w3.z + a3.w * w3.w;
        float accB = b0.x * w0.x + b0.y * w0.y + b0.z * w0.z + b0.w * w0.w
                   + b1.x * w1.x + b1.y * w1.y + b1.z * w1.z + b1.w * w1.w
                   + b2.x * w2.x + b2.y * w2.y + b2.z * w2.z + b2.w * w2.w
                   + b3.x * w3.x + b3.y * w3.y + b3.z * w3.z + b3.w * w3.w;
        // two independent reduce chains interleave
        for (int off = 32; off > 0; off >>= 1) {
            accA += __shfl_down(accA, off, 64);
            accB += __shfl_down(accB, off, 64);
        }
        if (lane == 0) { tok_dot[tokA] = accA; tok_dot[tokB] = accB; }
    }
}

// ---------------- Kernel 2: segment-sum + greedy selection + mask ------------
// One block per batch. Setup (stage + per-sentence sums) uses all 256 threads;
// the K-step loop runs entirely in wave 0 with register state (2 sentences per
// lane) and butterfly shfl_xor argmax -- no __syncthreads inside the loop.
__global__ void select_kernel(const float* __restrict__ tok_dot,  // [B,S]
                              const int* __restrict__ ind,        // [B,S]
                              const float* __restrict__ cls_b,    // [1]
                              float* __restrict__ out_selected,   // [B,N]
                              float* __restrict__ out_logits,     // [K,B,N]
                              float* __restrict__ out_mask) {     // [B,S]
    const int b = blockIdx.x;
    const int tid = threadIdx.x;  // 256 threads

    __shared__ float td[S_];
    __shared__ int   si[S_];
    __shared__ float sh_dseg[N_], sh_len[N_], sh_msk[N_], sh_sel[N_];

    for (int s = tid; s < S_; s += 256) {
        td[s] = tok_dot[b * S_ + s];
        si[s] = ind[b * S_ + s];
    }
    __syncthreads();

    if (tid < N_) {
        const int n = tid;
        int lo = 0, hi = S_;
        while (lo < hi) { int mid = (lo + hi) >> 1; if (si[mid] < n) lo = mid + 1; else hi = mid; }
        const int s0 = lo;
        lo = s0; hi = S_;
        while (lo < hi) { int mid = (lo + hi) >> 1; if (si[mid] < n + 1) lo = mid + 1; else hi = mid; }
        const int s1 = lo;
        float acc = 0.f;
        for (int s = s0; s < s1; ++s) acc += td[s];   // sorted order = ref assoc
        sh_dseg[tid] = acc;
        sh_len[tid]  = fmaxf((float)(s1 - s0), 1.0f);
        sh_msk[tid]  = (s1 > s0) ? 1.f : 0.f;
    }
    __syncthreads();

    if (tid < 64) {
        const float bias = cls_b[0];
        const float d0 = sh_dseg[tid],      d1 = sh_dseg[tid + 64];
        const float l0 = sh_len[tid],       l1 = sh_len[tid + 64];
        float m0 = sh_msk[tid],             m1 = sh_msk[tid + 64];
        float sel0 = 0.f, sel1 = 0.f;
        float dot = 0.f, len = 0.f;

        for (int k = 0; k < K_; ++k) {
            const float lg0 = (m0 > 0.f) ? (dot + d0) / (len + l0) + bias : NEG_INF_;
            const float lg1 = (m1 > 0.f) ? (dot + d1) / (len + l1) + bias : NEG_INF_;
            out_logits[(size_t)k * (B_ * N_) + b * N_ + tid]      = lg0;
            out_logits[(size_t)k * (B_ * N_) + b * N_ + tid + 64] = lg1;
            float bv; int bi;
            if (lg0 >= lg1) { bv = lg0; bi = tid; } else { bv = lg1; bi = tid + 64; }
            for (int off = 32; off > 0; off >>= 1) {
                const float ov = __shfl_xor(bv, off, 64);
                const int   oi = __shfl_xor(bi, off, 64);
                if (ov > bv || (ov == bv && oi < bi)) { bv = ov; bi = oi; }
            }
            // all lanes agree on (bv, bi); fetch picked sentence's dseg/len
            const float dsrc = (bi < 64) ? d0 : d1;   // uniform condition
            const float lsrc = (bi < 64) ? l0 : l1;
            dot += __shfl(dsrc, bi & 63, 64);
            len += __shfl(lsrc, bi & 63, 64);
            if ((bi & 63) == tid) {
                if (bi < 64) { m0 = 0.f; sel0 = 1.f; }
                else         { m1 = 0.f; sel1 = 1.f; }
            }
        }
        out_selected[b * N_ + tid]      = sel0;
        out_selected[b * N_ + tid + 64] = sel1;
        sh_sel[tid]      = sel0;
        sh_sel[tid + 64] = sel1;
    }
    __syncthreads();
    for (int s = tid; s < S_; s += 256) {
        out_mask[b * S_ + s] = sh_sel[si[s]];
    }
}

// ---------------- Kernel 3: write phase (mostly pure streaming stores) -------
// 8 tokens per block, 256 threads = one float4 per thread per token. Mask
// values prefetched up-front (broadcast loads). Zero path is store-only;
// selected path (~6% of tokens) copies h (L3-resident after kernel 1).
#define TPB_ 8
__global__ void write_kernel(const float* __restrict__ h,
                             const float* __restrict__ out_mask,  // [B,S]
                             float* __restrict__ out_masked) {    // [B,S,D]
    const int t0 = blockIdx.x * TPB_;
    const int tid = threadIdx.x;
    float m[TPB_];
    #pragma unroll
    for (int i = 0; i < TPB_; ++i) m[i] = out_mask[t0 + i];
    const float4 z = make_float4(0.f, 0.f, 0.f, 0.f);
    #pragma unroll
    for (int i = 0; i < TPB_; ++i) {
        const size_t base = (size_t)(t0 + i) * D_ + tid * 4;
        if (m[i] == 0.f) {
            *reinterpret_cast<float4*>(out_masked + base) = z;
        } else {
            *reinterpret_cast<float4*>(out_masked + base) =
                *reinterpret_cast<const float4*>(h + base);
        }
    }
}

extern "C" void kernel_launch(void* const* d_in, const int* in_sizes, int n_in,
                              void* d_out, int out_size, void* d_ws, size_t ws_size,
                              hipStream_t stream) {
    const float* h     = (const float*)d_in[0];
    const int*   ind   = (const int*)d_in[1];
    const float* cls_w = (const float*)d_in[2];
    const float* cls_b = (const float*)d_in[3];

    float* out = (float*)d_out;
    float* out_selected = out;                         // [B,N]    1024
    float* out_logits   = out + 1024;                  // [K,B,N]  8192
    float* out_mask     = out + 1024 + 8192;           // [B,S]    32768
    float* out_masked   = out + 1024 + 8192 + 32768;   // [B,S,D]

    float* tok_dot = (float*)d_ws;                     // B*S floats = 128 KB

    tok_dot_kernel<<<dim3(2048), dim3(256), 0, stream>>>(h, cls_w, tok_dot);
    select_kernel<<<dim3(B_), dim3(256), 0, stream>>>(tok_dot, ind, cls_b,
                                                      out_selected, out_logits,
                                                      out_mask);
    write_kernel<<<dim3(B_ * S_ / TPB_), dim3(256), 0, stream>>>(h, out_mask, out_masked);
}

// Round 7
// 56.383 us; speedup vs baseline: 1.1332x; 1.0052x over previous
//
#include <hip/hip_runtime.h>

#define B_ 8
#define S_ 4096
#define D_ 1024
#define N_ 128
#define K_ 8
#define NEG_INF_ (-1e9f)

// ---------------- Kernel 1: per-token dot with cls_w (pure-read phase) -------
// One wave per token-pair iteration: 2-token unroll keeps 8 float4 loads in
// flight before the shuffle reduce chains. 8192 waves, 32 waves/CU.
__global__ void tok_dot_kernel(const float* __restrict__ h,
                               const float* __restrict__ cls_w,
                               float* __restrict__ tok_dot) {   // [B*S]
    const int lane = threadIdx.x & 63;
    const int gw = (blockIdx.x << 2) + (threadIdx.x >> 6);  // 0..8191
    const int dofs = lane * 4;

    const float4 w0 = *reinterpret_cast<const float4*>(cls_w + 0 * 256 + dofs);
    const float4 w1 = *reinterpret_cast<const float4*>(cls_w + 1 * 256 + dofs);
    const float4 w2 = *reinterpret_cast<const float4*>(cls_w + 2 * 256 + dofs);
    const float4 w3 = *reinterpret_cast<const float4*>(cls_w + 3 * 256 + dofs);

    #pragma unroll
    for (int t = 0; t < 2; ++t) {
        const int tokA = gw + t * 16384;
        const int tokB = tokA + 8192;
        const float* pA = h + (size_t)tokA * D_;
        const float* pB = h + (size_t)tokB * D_;
        const float4 a0 = *reinterpret_cast<const float4*>(pA + 0 * 256 + dofs);
        const float4 a1 = *reinterpret_cast<const float4*>(pA + 1 * 256 + dofs);
        const float4 a2 = *reinterpret_cast<const float4*>(pA + 2 * 256 + dofs);
        const float4 a3 = *reinterpret_cast<const float4*>(pA + 3 * 256 + dofs);
        const float4 b0 = *reinterpret_cast<const float4*>(pB + 0 * 256 + dofs);
        const float4 b1 = *reinterpret_cast<const float4*>(pB + 1 * 256 + dofs);
        const float4 b2 = *reinterpret_cast<const float4*>(pB + 2 * 256 + dofs);
        const float4 b3 = *reinterpret_cast<const float4*>(pB + 3 * 256 + dofs);
        float accA = a0.x * w0.x + a0.y * w0.y + a0.z * w0.z + a0.w * w0.w
                   + a1.x * w1.x + a1.y * w1.y + a1.z * w1.z + a1.w * w1.w
                   + a2.x * w2.x + a2.y * w2.y + a2.z * w2.z + a2.w * w2.w
                   + a3.x * w3.x + a3.y * w3.y + a3.z * w3.z + a3.w * w3.w;
        float accB = b0.x * w0.x + b0.y * w0.y + b0.z * w0.z + b0.w * w0.w
                   + b1.x * w1.x + b1.y * w1.y + b1.z * w1.z + b1.w * w1.w
                   + b2.x * w2.x + b2.y * w2.y + b2.z * w2.z + b2.w * w2.w
                   + b3.x * w3.x + b3.y * w3.y + b3.z * w3.z + b3.w * w3.w;
        for (int off = 32; off > 0; off >>= 1) {
            accA += __shfl_down(accA, off, 64);
            accB += __shfl_down(accB, off, 64);
        }
        if (lane == 0) { tok_dot[tokA] = accA; tok_dot[tokB] = accB; }
    }
}

// ---------------- Kernel 2: segment-sum + greedy selection + mask ------------
// One block per batch. Segment sums use 2 threads/sentence (halved serial
// chain; reassociation error ~1e-7 << logit gaps). K-loop runs in wave 0 with
// register state and butterfly shfl_xor argmax -- no syncs inside the loop.
__global__ void select_kernel(const float* __restrict__ tok_dot,  // [B,S]
                              const int* __restrict__ ind,        // [B,S]
                              const float* __restrict__ cls_b,    // [1]
                              float* __restrict__ out_selected,   // [B,N]
                              float* __restrict__ out_logits,     // [K,B,N]
                              float* __restrict__ out_mask) {     // [B,S]
    const int b = blockIdx.x;
    const int tid = threadIdx.x;  // 256 threads

    __shared__ float td[S_];
    __shared__ int   si[S_];
    __shared__ float sh_part[256];
    __shared__ int   sh_s0[N_], sh_s1[N_];
    __shared__ float sh_dseg[N_], sh_len[N_], sh_msk[N_], sh_sel[N_];

    for (int s = tid; s < S_; s += 256) {
        td[s] = tok_dot[b * S_ + s];
        si[s] = ind[b * S_ + s];
    }
    __syncthreads();

    // 2 threads per sentence: thread n sums [s0,mid), thread n+128 sums [mid,s1)
    {
        const int n = tid & (N_ - 1);
        int lo = 0, hi = S_;
        while (lo < hi) { int mid = (lo + hi) >> 1; if (si[mid] < n) lo = mid + 1; else hi = mid; }
        const int s0 = lo;
        lo = s0; hi = S_;
        while (lo < hi) { int mid = (lo + hi) >> 1; if (si[mid] < n + 1) lo = mid + 1; else hi = mid; }
        const int s1 = lo;
        const int mid = (s0 + s1) >> 1;
        const int a = (tid < N_) ? s0 : mid;
        const int e = (tid < N_) ? mid : s1;
        float acc = 0.f;
        for (int s = a; s < e; ++s) acc += td[s];
        sh_part[tid] = acc;
        if (tid < N_) { sh_s0[tid] = s0; sh_s1[tid] = s1; }
    }
    __syncthreads();
    if (tid < N_) {
        const int s0 = sh_s0[tid], s1 = sh_s1[tid];
        sh_dseg[tid] = sh_part[tid] + sh_part[tid + N_];
        sh_len[tid]  = fmaxf((float)(s1 - s0), 1.0f);
        sh_msk[tid]  = (s1 > s0) ? 1.f : 0.f;
    }
    __syncthreads();

    if (tid < 64) {
        const float bias = cls_b[0];
        const float d0 = sh_dseg[tid],      d1 = sh_dseg[tid + 64];
        const float l0 = sh_len[tid],       l1 = sh_len[tid + 64];
        float m0 = sh_msk[tid],             m1 = sh_msk[tid + 64];
        float sel0 = 0.f, sel1 = 0.f;
        float dot = 0.f, len = 0.f;

        for (int k = 0; k < K_; ++k) {
            const float lg0 = (m0 > 0.f) ? (dot + d0) / (len + l0) + bias : NEG_INF_;
            const float lg1 = (m1 > 0.f) ? (dot + d1) / (len + l1) + bias : NEG_INF_;
            out_logits[(size_t)k * (B_ * N_) + b * N_ + tid]      = lg0;
            out_logits[(size_t)k * (B_ * N_) + b * N_ + tid + 64] = lg1;
            float bv; int bi;
            if (lg0 >= lg1) { bv = lg0; bi = tid; } else { bv = lg1; bi = tid + 64; }
            for (int off = 32; off > 0; off >>= 1) {
                const float ov = __shfl_xor(bv, off, 64);
                const int   oi = __shfl_xor(bi, off, 64);
                if (ov > bv || (ov == bv && oi < bi)) { bv = ov; bi = oi; }
            }
            const float dsrc = (bi < 64) ? d0 : d1;   // uniform condition
            const float lsrc = (bi < 64) ? l0 : l1;
            dot += __shfl(dsrc, bi & 63, 64);
            len += __shfl(lsrc, bi & 63, 64);
            if ((bi & 63) == tid) {
                if (bi < 64) { m0 = 0.f; sel0 = 1.f; }
                else         { m1 = 0.f; sel1 = 1.f; }
            }
        }
        out_selected[b * N_ + tid]      = sel0;
        out_selected[b * N_ + tid + 64] = sel1;
        sh_sel[tid]      = sel0;
        sh_sel[tid + 64] = sel1;
    }
    __syncthreads();
    for (int s = tid; s < S_; s += 256) {
        out_mask[b * S_ + s] = sh_sel[si[s]];
    }
}

// ---------------- Kernel 3: write phase (pure streaming stores) --------------
// 16 tokens per block -> 2048 blocks = exactly 32 resident waves/CU (one
// cohort). Zeros-loop first (unbroken store stream, the ~94% common case),
// then the copy-loop for selected tokens (h is L3-resident).
#define TPB_ 16
__global__ void write_kernel(const float* __restrict__ h,
                             const float* __restrict__ out_mask,  // [B,S]
                             float* __restrict__ out_masked) {    // [B,S,D]
    const int t0 = blockIdx.x * TPB_;
    const int tid = threadIdx.x;
    float m[TPB_];
    #pragma unroll
    for (int i = 0; i < TPB_; ++i) m[i] = out_mask[t0 + i];
    const float4 z = make_float4(0.f, 0.f, 0.f, 0.f);
    #pragma unroll
    for (int i = 0; i < TPB_; ++i) {
        if (m[i] == 0.f) {
            const size_t base = (size_t)(t0 + i) * D_ + tid * 4;
            *reinterpret_cast<float4*>(out_masked + base) = z;
        }
    }
    #pragma unroll
    for (int i = 0; i < TPB_; ++i) {
        if (m[i] != 0.f) {
            const size_t base = (size_t)(t0 + i) * D_ + tid * 4;
            *reinterpret_cast<float4*>(out_masked + base) =
                *reinterpret_cast<const float4*>(h + base);
        }
    }
}

extern "C" void kernel_launch(void* const* d_in, const int* in_sizes, int n_in,
                              void* d_out, int out_size, void* d_ws, size_t ws_size,
                              hipStream_t stream) {
    const float* h     = (const float*)d_in[0];
    const int*   ind   = (const int*)d_in[1];
    const float* cls_w = (const float*)d_in[2];
    const float* cls_b = (const float*)d_in[3];

    float* out = (float*)d_out;
    float* out_selected = out;                         // [B,N]    1024
    float* out_logits   = out + 1024;                  // [K,B,N]  8192
    float* out_mask     = out + 1024 + 8192;           // [B,S]    32768
    float* out_masked   = out + 1024 + 8192 + 32768;   // [B,S,D]

    float* tok_dot = (float*)d_ws;                     // B*S floats = 128 KB

    tok_dot_kernel<<<dim3(2048), dim3(256), 0, stream>>>(h, cls_w, tok_dot);
    select_kernel<<<dim3(B_), dim3(256), 0, stream>>>(tok_dot, ind, cls_b,
                                                      out_selected, out_logits,
                                                      out_mask);
    write_kernel<<<dim3(B_ * S_ / TPB_), dim3(256), 0, stream>>>(h, out_mask, out_masked);
}